// Round 13
// baseline (224.160 us; speedup 1.0000x reference)
//
#include <hip/hip_runtime.h>
#include <hip/hip_bf16.h>
#include <stdint.h>

typedef __bf16 bf16x8 __attribute__((ext_vector_type(8)));
typedef float f32x4 __attribute__((ext_vector_type(4)));
typedef float f32x16 __attribute__((ext_vector_type(16)));
typedef unsigned int uint2v __attribute__((ext_vector_type(2)));

#define E_DIM 1024
#define HD 64
#define NH 16
#define QKV_LD 1152
#define KSPLIT 2
#define LOG2E 1.44269504088896f

__device__ __forceinline__ float toF(float x) { return x; }
__device__ __forceinline__ float toF(__hip_bfloat16 x) { return __bfloat162float(x); }
__device__ __forceinline__ void storeOut(float* p, float v) { *p = v; }
__device__ __forceinline__ void storeOut(__hip_bfloat16* p, float v) { *p = __float2bfloat16(v); }

__device__ __forceinline__ unsigned cvtpk_bf16(float lo, float hi_) {
    unsigned r;
    asm("v_cvt_pk_bf16_f32 %0, %1, %2" : "=v"(r) : "v"(lo), "v"(hi_));
    return r;
}
__device__ __forceinline__ void perm32swap(unsigned& a, unsigned& b) {
    uint2v r = __builtin_amdgcn_permlane32_swap(a, b, false, false);
    a = r.x; b = r.y;
}
__device__ __forceinline__ float fexp2(float x) {
    float r;
    asm("v_exp_f32 %0, %1" : "=v"(r) : "v"(x));
    return r;
}

typedef __attribute__((address_space(1))) void gvoid;
typedef __attribute__((address_space(3))) void lvoid;
__device__ __forceinline__ void gload_lds16(const void* g, void* l) {
    __builtin_amdgcn_global_load_lds((gvoid*)g, (lvoid*)l, 16, 0, 0);
}

// ---------------- cast fp32 -> bf16 (vectorized) ----------------
__global__ void cast_f32_bf16_kernel(const float* __restrict__ in, __hip_bfloat16* __restrict__ o, int n) {
    int i = (blockIdx.x * blockDim.x + threadIdx.x) * 4;
    if (i + 3 < n) {
        float4 v = *reinterpret_cast<const float4*>(in + i);
        __hip_bfloat16 t[4] = {__float2bfloat16(v.x), __float2bfloat16(v.y),
                               __float2bfloat16(v.z), __float2bfloat16(v.w)};
        *reinterpret_cast<uint2*>(o + i) = *reinterpret_cast<uint2*>(t);
    }
}

// ---------------- tiled cast-transpose: out[c][r] = in[r][c] ----------------
template<typename InT>
__global__ void transpose_cast_kernel(const InT* __restrict__ in, int ldi,
                                      __hip_bfloat16* __restrict__ out, int ldo,
                                      int R, int C) {
    __shared__ float tile[32][33];
    const int bx = blockIdx.x * 32;  // r
    const int by = blockIdx.y * 32;  // c
    const int tx = threadIdx.x & 31, ty = threadIdx.x >> 5;  // 32 x 8
#pragma unroll
    for (int j = 0; j < 4; ++j) {
        int r = bx + ty + j * 8, c = by + tx;
        tile[ty + j * 8][tx] = toF(in[(size_t)r * ldi + c]);
    }
    __syncthreads();
#pragma unroll
    for (int j = 0; j < 4; ++j) {
        int c = by + ty + j * 8, r = bx + tx;
        out[(size_t)c * ldo + r] = __float2bfloat16(tile[tx][ty + j * 8]);
    }
}

// ---------------- all 4 weight transposes in one launch (grid.z selects) ----------------
__global__ __launch_bounds__(256)
void transpose4_kernel(const float* __restrict__ Wq, const float* __restrict__ Wk,
                       const float* __restrict__ Wv, const float* __restrict__ Wo,
                       __hip_bfloat16* __restrict__ wqkvT, __hip_bfloat16* __restrict__ woT) {
    const int z = blockIdx.z;
    const float* in; __hip_bfloat16* out; int ldi;
    if (z == 0)      { in = Wq; out = wqkvT;                                ldi = E_DIM; }
    else if (z == 1) { if (blockIdx.y >= HD / 32) return;
                       in = Wk; out = wqkvT + (size_t)E_DIM * E_DIM;        ldi = HD; }
    else if (z == 2) { if (blockIdx.y >= HD / 32) return;
                       in = Wv; out = wqkvT + (size_t)(E_DIM + HD) * E_DIM; ldi = HD; }
    else             { in = Wo; out = woT;                                  ldi = E_DIM; }
    __shared__ float tile[32][33];
    const int bx = blockIdx.x * 32;  // input row
    const int by = blockIdx.y * 32;  // input col
    const int tx = threadIdx.x & 31, ty = threadIdx.x >> 5;
#pragma unroll
    for (int j = 0; j < 4; ++j) {
        int r = bx + ty + j * 8, c = by + tx;
        tile[ty + j * 8][tx] = in[(size_t)r * ldi + c];
    }
    __syncthreads();
#pragma unroll
    for (int j = 0; j < 4; ++j) {
        int c = by + ty + j * 8, r = bx + tx;
        out[(size_t)c * E_DIM + r] = __float2bfloat16(tile[tx][ty + j * 8]);
    }
}

// ---------------- bqkv = [bq | bk | bv] ----------------
__global__ void concat_bias3_kernel(const float* __restrict__ bq, const float* __restrict__ bk,
                                    const float* __restrict__ bv, float* __restrict__ bqkv) {
    int i = blockIdx.x * blockDim.x + threadIdx.x;
    if (i < E_DIM) bqkv[i] = bq[i];
    else if (i < E_DIM + HD) bqkv[i] = bk[i - E_DIM];
    else if (i < E_DIM + 2 * HD) bqkv[i] = bv[i - E_DIM - HD];
}

// ---------------- mask -> 64-bit words via ballot ----------------
__global__ void maskbits_kernel(const int* __restrict__ mask, unsigned long long* __restrict__ mb,
                                int nwords) {
    int gtid = blockIdx.x * blockDim.x + threadIdx.x;
    int wid = gtid >> 6, lane = gtid & 63;
    int nw = (gridDim.x * blockDim.x) >> 6;
    for (int w = wid; w < nwords; w += nw) {
        int v = mask[(size_t)w * 64 + lane];
        unsigned long long b = __ballot(v != 0);
        if (lane == 0) mb[w] = b;
    }
}

// ---------------- bf16 GEMM v3: 64x128 tile, BK=64, gload_lds staging (r11 best) ----------------
template<typename OutT>
__global__ __launch_bounds__(256)
void gemm_bt3_kernel(const __hip_bfloat16* __restrict__ A,
                     const __hip_bfloat16* __restrict__ Bt,
                     const float* __restrict__ bias,
                     OutT* __restrict__ C,
                     int M, int N, int K, float sQ, int nQ, float sKV) {
    constexpr int BM = 64, BN = 128, BK = 64;
    __shared__ __align__(16) unsigned char lA[2][BM * BK * 2];   // 8KB each
    __shared__ __align__(16) unsigned char lB[2][BN * BK * 2];   // 16KB each
    const int ntn = N / BN;
    const int tm = blockIdx.x / ntn, tn = blockIdx.x % ntn;
    const int tid = threadIdx.x, lane = tid & 63, wave = tid >> 6;
    const int l15 = lane & 15, l4 = lane >> 4;
    const int wm = (wave >> 1) * 32, wn = (wave & 1) * 64;
    const int r0 = tm * BM, c0 = tn * BN;
    const int NK = K / BK;

    size_t aoff[2]; unsigned ldsoA[2];
    size_t boff[4]; unsigned ldsoB[4];
#pragma unroll
    for (int i = 0; i < 2; ++i) {
        int row = wave * 16 + i * 8 + (lane >> 3);
        int c = (lane & 7) ^ (row & 7);
        aoff[i] = (size_t)(r0 + row) * K * 2 + c * 16;
        ldsoA[i] = wave * 2048 + i * 1024;
    }
#pragma unroll
    for (int i = 0; i < 4; ++i) {
        int row = wave * 32 + i * 8 + (lane >> 3);
        int c = (lane & 7) ^ (row & 7);
        boff[i] = (size_t)(c0 + row) * K * 2 + c * 16;
        ldsoB[i] = wave * 4096 + i * 1024;
    }
    const char* Ab = (const char*)A;
    const char* Bb = (const char*)Bt;

#pragma unroll
    for (int i = 0; i < 2; ++i) gload_lds16(Ab + aoff[i], &lA[0][ldsoA[i]]);
#pragma unroll
    for (int i = 0; i < 4; ++i) gload_lds16(Bb + boff[i], &lB[0][ldsoB[i]]);
    __syncthreads();

    f32x4 z4 = {0.f, 0.f, 0.f, 0.f};
    f32x4 acc[2][4];
#pragma unroll
    for (int mi = 0; mi < 2; ++mi)
#pragma unroll
        for (int ni = 0; ni < 4; ++ni) acc[mi][ni] = z4;

    int buf = 0;
    for (int ks = 0; ks < NK; ++ks) {
        if (ks + 1 < NK) {
            size_t kb = (size_t)(ks + 1) * BK * 2;
#pragma unroll
            for (int i = 0; i < 2; ++i) gload_lds16(Ab + aoff[i] + kb, &lA[buf ^ 1][ldsoA[i]]);
#pragma unroll
            for (int i = 0; i < 4; ++i) gload_lds16(Bb + boff[i] + kb, &lB[buf ^ 1][ldsoB[i]]);
        }
        bf16x8 af[2][2], bf[4][2];
#pragma unroll
        for (int mi = 0; mi < 2; ++mi) {
            int row = wm + mi * 16 + l15;
#pragma unroll
            for (int kh = 0; kh < 2; ++kh) {
                int slot = (kh * 4 + l4) ^ (row & 7);
                af[mi][kh] = *reinterpret_cast<const bf16x8*>(&lA[buf][row * 128 + slot * 16]);
            }
        }
#pragma unroll
        for (int ni = 0; ni < 4; ++ni) {
            int row = wn + ni * 16 + l15;
#pragma unroll
            for (int kh = 0; kh < 2; ++kh) {
                int slot = (kh * 4 + l4) ^ (row & 7);
                bf[ni][kh] = *reinterpret_cast<const bf16x8*>(&lB[buf][row * 128 + slot * 16]);
            }
        }
        __builtin_amdgcn_s_setprio(1);
#pragma unroll
        for (int mi = 0; mi < 2; ++mi)
#pragma unroll
            for (int ni = 0; ni < 4; ++ni) {
                acc[mi][ni] = __builtin_amdgcn_mfma_f32_16x16x32_bf16(af[mi][0], bf[ni][0], acc[mi][ni], 0, 0, 0);
                acc[mi][ni] = __builtin_amdgcn_mfma_f32_16x16x32_bf16(af[mi][1], bf[ni][1], acc[mi][ni], 0, 0, 0);
            }
        __builtin_amdgcn_s_setprio(0);
        __syncthreads();
        buf ^= 1;
    }

#pragma unroll
    for (int ni = 0; ni < 4; ++ni) {
        int col = c0 + wn + ni * 16 + l15;
        float b = bias[col];
        float s = (col < nQ) ? sQ : sKV;
#pragma unroll
        for (int mi = 0; mi < 2; ++mi) {
            int row = r0 + wm + mi * 16 + l4 * 4;
#pragma unroll
            for (int r = 0; r < 4; ++r) {
                float v = (acc[mi][ni][r] + b) * s;
                storeOut(C + (size_t)(row + r) * N + col, v);
            }
        }
    }
}

// ---------------- MQA flash attention v11: K-split + static-max softmax ----------------
// grid (S/32, NH/4, KSPLIT). 4 waves/block, wave = head, 32 q-rows, 64-key tiles.
// Static-max: p = exp2(s) directly; splits share the implicit zero max, so the
// combine is a pure add: O = (O0+O1)/(l0+l1). KSPLIT doubles wave count ->
// 16 waves/CU nominal; launch_bounds(256,3) targets 3 waves/SIMD (regs <= 170).
// LDS tile: 64 rows x 256B (2 x 16KB dbuf). Row r: chunks 0..7 = K[k0+r][0:64];
// chunks 8..15 = Vt[d=r][k0..k0+64]. Chunk c at slot c ^ (r&15) (pre-swizzled source).
__global__ __launch_bounds__(256, 3)
void mqa11_kernel(const __hip_bfloat16* __restrict__ qkv,   // [S][1152], q prescaled
                  const __hip_bfloat16* __restrict__ vtb,   // [64][S]
                  const unsigned long long* __restrict__ mbits,
                  float* __restrict__ po,                   // [KSPLIT][S][1024] unnormalized
                  float* __restrict__ ml,                   // [KSPLIT][S][NH] row-sums
                  int S) {
    __shared__ __align__(16) unsigned char sKV[2][16384];
    const int tid = threadIdx.x, lane = tid & 63, w = tid >> 6;
    const int r31 = lane & 31, hi = lane >> 5, rx = r31 & 15;
    const int q0 = blockIdx.x * 32;
    const int h = blockIdx.y * 4 + w;
    const int split = blockIdx.z;
    const int NW64 = S / 64;
    const int NT = NW64 / KSPLIT;          // 64-key tiles per split
    const int k0base = split * (S / KSPLIT);
    const __hip_bfloat16* kvb = qkv + E_DIM;

    // Q fragments (prescaled by 0.125*log2e in the fused GEMM)
    bf16x8 qf[4];
    {
        const __hip_bfloat16* qp = qkv + (size_t)(q0 + r31) * QKV_LD + h * HD + hi * 8;
#pragma unroll
        for (int s = 0; s < 4; ++s) qf[s] = *reinterpret_cast<const bf16x8*>(qp + 16 * s);
    }
    bf16x8 ones;
#pragma unroll
    for (int i = 0; i < 8; ++i) ones[i] = (__bf16)1.0f;

    // staging: wave w owns tile rows [w*16, w*16+16) -> 4 x 1KB global_load_lds_dwordx4
    const char* gbase[4];
    int gstep[4];
    unsigned ldsoff[4];
#pragma unroll
    for (int i = 0; i < 4; ++i) {
        int r = w * 16 + i * 4 + (lane >> 4);
        int sl = lane & 15;            // LDS 16B slot within row
        int c = sl ^ (r & 15);         // global chunk that lands in this slot
        if (c < 8) {
            gbase[i] = (const char*)(kvb + (size_t)(k0base + r) * QKV_LD + c * 8);
            gstep[i] = 64 * QKV_LD * 2;
        } else {
            gbase[i] = (const char*)(vtb + (size_t)r * S + k0base + (c - 8) * 8);
            gstep[i] = 64 * 2;
        }
        ldsoff[i] = w * 4096 + i * 1024;
    }

    // prologue: stage tile 0
#pragma unroll
    for (int i = 0; i < 4; ++i) { gload_lds16(gbase[i], &sKV[0][ldsoff[i]]); gbase[i] += gstep[i]; }
    __syncthreads();

    f32x16 oacc[2], lacc;
#pragma unroll
    for (int i = 0; i < 16; ++i) { oacc[0][i] = 0.f; oacc[1][i] = 0.f; lacc[i] = 0.f; }

    const size_t mrow = (size_t)(q0 + r31) * NW64 + (size_t)split * NT;
    int buf = 0;
    for (int t = 0; t < NT; ++t) {
        // mask word FIRST (so waiting on it never drains the staging queue)
        unsigned long long wb = mbits[mrow + t];
        // stage tile t+1 into other buffer (drained by end-of-iter barrier)
        if (t + 1 < NT) {
#pragma unroll
            for (int i = 0; i < 4; ++i) { gload_lds16(gbase[i], &sKV[buf ^ 1][ldsoff[i]]); gbase[i] += gstep[i]; }
        }
        const unsigned char* bp = sKV[buf];

        // ---- QK^T: sacc[kb][reg] = S_log2[k = kb*32 + crow(reg,hi)][q = r31]
        f32x16 sacc[2];
        __builtin_amdgcn_s_setprio(1);
#pragma unroll
        for (int kb = 0; kb < 2; ++kb) {
            const unsigned char* rowp = bp + (kb * 32 + r31) * 256;
            f32x16 a;
#pragma unroll
            for (int i = 0; i < 16; ++i) a[i] = 0.f;
#pragma unroll
            for (int s = 0; s < 4; ++s) {
                int slot = (2 * s + hi) ^ rx;
                bf16x8 kf = *reinterpret_cast<const bf16x8*>(rowp + slot * 16);
                a = __builtin_amdgcn_mfma_f32_32x32x16_bf16(kf, qf[s], a, 0, 0, 0);
            }
            sacc[kb] = a;
        }
        __builtin_amdgcn_s_setprio(0);

        // ---- mask (free when all-ones); -10000 * log2e -> exp2 gives exact 0
        if (wb != ~0ull) {
#pragma unroll
            for (int kb = 0; kb < 2; ++kb) {
                int base = kb * 32;
#pragma unroll
                for (int r = 0; r < 16; ++r) {
                    int kl = base + (r & 3) + 8 * (r >> 2) + 4 * hi;
                    if (!((wb >> kl) & 1)) sacc[kb][r] = -14427.0f;
                }
            }
        }

        // ---- p = exp2(s) directly (softmax scale-invariance; no max needed)
#pragma unroll
        for (int kb = 0; kb < 2; ++kb)
#pragma unroll
            for (int r = 0; r < 16; ++r) sacc[kb][r] = fexp2(sacc[kb][r]);

        // ---- P -> bf16 A-frags: pa[kb*2+half] holds P[q][k = 16s + hi*8 + j]
        bf16x8 pa[4];
#pragma unroll
        for (int kb = 0; kb < 2; ++kb) {
#pragma unroll
            for (int half = 0; half < 2; ++half) {
                int b0 = half * 8;
                const f32x16& sv = sacc[kb];
                unsigned A = cvtpk_bf16(sv[b0 + 0], sv[b0 + 1]);
                unsigned B = cvtpk_bf16(sv[b0 + 2], sv[b0 + 3]);
                unsigned C = cvtpk_bf16(sv[b0 + 4], sv[b0 + 5]);
                unsigned D = cvtpk_bf16(sv[b0 + 6], sv[b0 + 7]);
                perm32swap(A, C);
                perm32swap(B, D);
                union { unsigned u[4]; bf16x8 v; } pk;
                pk.u[0] = A; pk.u[1] = B; pk.u[2] = C; pk.u[3] = D;
                pa[kb * 2 + half] = pk.v;
            }
        }

        // ---- PV (Oᵀ) + lacc ones-MFMA rowsum
        __builtin_amdgcn_s_setprio(1);
#pragma unroll
        for (int db = 0; db < 2; ++db) {
            const unsigned char* rowp = bp + (db * 32 + r31) * 256;
            f32x16 a = oacc[db];
#pragma unroll
            for (int s = 0; s < 4; ++s) {
                int slot = (8 + 2 * s + hi) ^ rx;
                bf16x8 vf = *reinterpret_cast<const bf16x8*>(rowp + slot * 16);
                a = __builtin_amdgcn_mfma_f32_32x32x16_bf16(vf, pa[s], a, 0, 0, 0);
            }
            oacc[db] = a;
        }
#pragma unroll
        for (int s = 0; s < 4; ++s)
            lacc = __builtin_amdgcn_mfma_f32_32x32x16_bf16(ones, pa[s], lacc, 0, 0, 0);
        __builtin_amdgcn_s_setprio(0);

        __syncthreads();
        buf ^= 1;
    }

    // ---- epilogue: write unnormalized O partial (fp32) + row-sum l
    const int q = q0 + r31;
    float* pop = po + (size_t)split * S * E_DIM + (size_t)q * E_DIM + h * HD;
#pragma unroll
    for (int db = 0; db < 2; ++db)
#pragma unroll
        for (int m = 0; m < 4; ++m) {
            float4 v4 = {oacc[db][4 * m + 0], oacc[db][4 * m + 1],
                         oacc[db][4 * m + 2], oacc[db][4 * m + 3]};
            *reinterpret_cast<float4*>(pop + db * 32 + m * 8 + hi * 4) = v4;
        }
    if (hi == 0) ml[((size_t)split * S + q) * NH + h] = lacc[0];
}

// ---------------- combine K-split partials (pure add) -> bf16 attnb ----------------
__global__ __launch_bounds__(256)
void combine2_kernel(const float* __restrict__ po, const float* __restrict__ ml,
                     __hip_bfloat16* __restrict__ attnb, int S) {
    int i4 = (blockIdx.x * blockDim.x + threadIdx.x) * 4;   // over S*1024
    int q = i4 >> 10, h = (i4 & 1023) >> 6;
    float l = ml[(size_t)q * NH + h] + ml[((size_t)S + q) * NH + h];
    float4 a = *reinterpret_cast<const float4*>(po + i4);
    float4 b = *reinterpret_cast<const float4*>(po + (size_t)S * E_DIM + i4);
    float inv = 1.0f / l;
    uint2 pk;
    pk.x = cvtpk_bf16((a.x + b.x) * inv, (a.y + b.y) * inv);
    pk.y = cvtpk_bf16((a.z + b.z) * inv, (a.w + b.w) * inv);
    *reinterpret_cast<uint2*>(attnb + i4) = pk;
}

// ---------------- host launch ----------------
extern "C" void kernel_launch(void* const* d_in, const int* in_sizes, int n_in,
                              void* d_out, int out_size, void* d_ws, size_t ws_size,
                              hipStream_t stream) {
    (void)n_in; (void)out_size; (void)ws_size;
    const float* x  = (const float*)d_in[0];
    const int* mask = (const int*)d_in[1];
    const float* Wq = (const float*)d_in[2];
    const float* bq = (const float*)d_in[3];
    const float* Wk = (const float*)d_in[4];
    const float* bk = (const float*)d_in[5];
    const float* Wv = (const float*)d_in[6];
    const float* bv = (const float*)d_in[7];
    const float* Wo = (const float*)d_in[8];
    const float* bo = (const float*)d_in[9];
    float* out = (float*)d_out;

    const int E = E_DIM;
    const int S = in_sizes[0] / E;

    char* ws = (char*)d_ws;
    size_t off = 0;
    auto alloc = [&](size_t b) { char* p = ws + off; off += (b + 255) & ~(size_t)255; return p; };
    __hip_bfloat16* xb     = (__hip_bfloat16*)alloc((size_t)S * E * 2);
    __hip_bfloat16* wqkvT  = (__hip_bfloat16*)alloc((size_t)QKV_LD * E * 2);  // [Wq^T;Wk^T;Wv^T]
    __hip_bfloat16* woT    = (__hip_bfloat16*)alloc((size_t)E * E * 2);
    __hip_bfloat16* qkvb   = (__hip_bfloat16*)alloc((size_t)S * QKV_LD * 2);
    __hip_bfloat16* vtb    = (__hip_bfloat16*)alloc((size_t)HD * S * 2);
    __hip_bfloat16* attnb  = (__hip_bfloat16*)alloc((size_t)S * E * 2);
    float* bqkv  = (float*)alloc(QKV_LD * 4);
    float* po    = (float*)alloc((size_t)KSPLIT * S * E * 4);
    float* ml    = (float*)alloc((size_t)KSPLIT * S * NH * 4);
    unsigned long long* mbits = (unsigned long long*)alloc((size_t)S * (S / 64) * 8);

    cast_f32_bf16_kernel<<<dim3((S * E / 4 + 255) / 256), dim3(256), 0, stream>>>(x, xb, S * E);
    transpose4_kernel<<<dim3(E / 32, E / 32, 4), dim3(256), 0, stream>>>(Wq, Wk, Wv, Wo, wqkvT, woT);
    concat_bias3_kernel<<<dim3((QKV_LD + 255) / 256), dim3(256), 0, stream>>>(bq, bk, bv, bqkv);
    maskbits_kernel<<<dim3(1024), dim3(256), 0, stream>>>(mask, mbits, S * (S / 64));

    // fused qkv = x @ [Wq|Wk|Wv] + [bq|bk|bv]; q-part scaled by 1/8*log2e -> bf16 [S][1152]
    gemm_bt3_kernel<__hip_bfloat16><<<dim3((S / 64) * (QKV_LD / 128)), dim3(256), 0, stream>>>(
        xb, wqkvT, bqkv, qkvb, S, QKV_LD, E, 0.125f * LOG2E, E, 1.0f);
    // v^T [64][S] from qkv columns 1088..1151
    transpose_cast_kernel<__hip_bfloat16><<<dim3(S / 32, HD / 32), dim3(256), 0, stream>>>(
        qkvb + E + HD, QKV_LD, vtb, S, S, HD);
    // attention partials (K-split, static-max)
    mqa11_kernel<<<dim3(S / 32, NH / 4, KSPLIT), dim3(256), 0, stream>>>(
        qkvb, vtb, mbits, po, ml, S);
    // combine partials -> bf16 attnb
    combine2_kernel<<<dim3(S * E / (256 * 4)), dim3(256), 0, stream>>>(po, ml, attnb, S);
    // out = attn @ Wo + bo  (fp32)
    gemm_bt3_kernel<float><<<dim3((S / 64) * (E / 128)), dim3(256), 0, stream>>>(
        attnb, woT, bo, out, S, E, E, 1.0f, E, 1.0f);
}

// Round 14
// 158.574 us; speedup vs baseline: 1.4136x; 1.4136x over previous
//
#include <hip/hip_runtime.h>
#include <hip/hip_bf16.h>
#include <stdint.h>

typedef __bf16 bf16x8 __attribute__((ext_vector_type(8)));
typedef float f32x4 __attribute__((ext_vector_type(4)));
typedef float f32x16 __attribute__((ext_vector_type(16)));
typedef unsigned int uint2v __attribute__((ext_vector_type(2)));

#define E_DIM 1024
#define HD 64
#define NH 16
#define QKV_LD 1152
#define LOG2E 1.44269504088896f

__device__ __forceinline__ void storeOut(float* p, float v) { *p = v; }
__device__ __forceinline__ void storeOut(__hip_bfloat16* p, float v) { *p = __float2bfloat16(v); }

__device__ __forceinline__ unsigned cvtpk_bf16(float lo, float hi_) {
    unsigned r;
    asm("v_cvt_pk_bf16_f32 %0, %1, %2" : "=v"(r) : "v"(lo), "v"(hi_));
    return r;
}
__device__ __forceinline__ void perm32swap(unsigned& a, unsigned& b) {
    uint2v r = __builtin_amdgcn_permlane32_swap(a, b, false, false);
    a = r.x; b = r.y;
}
__device__ __forceinline__ float fexp2(float x) {
    float r;
    asm("v_exp_f32 %0, %1" : "=v"(r) : "v"(x));
    return r;
}

typedef __attribute__((address_space(1))) void gvoid;
typedef __attribute__((address_space(3))) void lvoid;
__device__ __forceinline__ void gload_lds16(const void* g, void* l) {
    __builtin_amdgcn_global_load_lds((gvoid*)g, (lvoid*)l, 16, 0, 0);
}

// ---------------- fused prep: cast | maskbits | 4 weight transposes | bias concat ----------------
// One launch; block ranges select the role so the BW-bound mask scan co-schedules
// with the transpose/cast work instead of serializing across 7 dispatches.
__global__ __launch_bounds__(256)
void prep_kernel(const float* __restrict__ x, __hip_bfloat16* __restrict__ xb,
                 const int* __restrict__ mask, unsigned long long* __restrict__ mbits,
                 const float* __restrict__ Wq, const float* __restrict__ Wk,
                 const float* __restrict__ Wv, const float* __restrict__ Wo,
                 __hip_bfloat16* __restrict__ wqkvT, __hip_bfloat16* __restrict__ woT,
                 const float* __restrict__ bq, const float* __restrict__ bk,
                 const float* __restrict__ bv, float* __restrict__ bqkv,
                 int S) {
    __shared__ float tile[32][33];
    const int tid = threadIdx.x;
    const int castBlocks = S * E_DIM / 1024;   // 256 threads x float4 each
    const int maskBlocks = 1024;
    int bid = blockIdx.x;

    if (bid < castBlocks) {                    // ---- cast fp32 -> bf16
        int i = (bid * 256 + tid) * 4;
        float4 v = *reinterpret_cast<const float4*>(x + i);
        __hip_bfloat16 t[4] = {__float2bfloat16(v.x), __float2bfloat16(v.y),
                               __float2bfloat16(v.z), __float2bfloat16(v.w)};
        *reinterpret_cast<uint2*>(xb + i) = *reinterpret_cast<uint2*>(t);
        return;
    }
    bid -= castBlocks;
    if (bid < maskBlocks) {                    // ---- mask -> 64-bit ballot words
        int gtid = bid * 256 + tid;
        int wid = gtid >> 6, lane = gtid & 63;
        int nw = (maskBlocks * 256) >> 6;
        int nwords = S * (S / 64);
        for (int w = wid; w < nwords; w += nw) {
            int v = mask[(size_t)w * 64 + lane];
            unsigned long long b = __ballot(v != 0);
            if (lane == 0) mbits[w] = b;
        }
        return;
    }
    bid -= maskBlocks;
    if (bid < 2176) {                          // ---- weight cast-transposes
        const float* in; __hip_bfloat16* out; int ldi, bx, by;
        if (bid < 1024)      { in = Wq; out = wqkvT;                                ldi = E_DIM; bx = bid >> 5; by = bid & 31; }
        else if (bid < 1088) { int t2 = bid - 1024;
                               in = Wk; out = wqkvT + (size_t)E_DIM * E_DIM;        ldi = HD;    bx = t2 >> 1;  by = t2 & 1; }
        else if (bid < 1152) { int t2 = bid - 1088;
                               in = Wv; out = wqkvT + (size_t)(E_DIM + HD) * E_DIM; ldi = HD;    bx = t2 >> 1;  by = t2 & 1; }
        else                 { int t2 = bid - 1152;
                               in = Wo; out = woT;                                  ldi = E_DIM; bx = t2 >> 5; by = t2 & 31; }
        const int tx = tid & 31, ty = tid >> 5;
#pragma unroll
        for (int j = 0; j < 4; ++j) {
            int r = bx * 32 + ty + j * 8, c = by * 32 + tx;
            tile[ty + j * 8][tx] = in[(size_t)r * ldi + c];
        }
        __syncthreads();
#pragma unroll
        for (int j = 0; j < 4; ++j) {
            int c = by * 32 + ty + j * 8, r = bx * 32 + tx;
            out[(size_t)c * E_DIM + r] = __float2bfloat16(tile[tx][ty + j * 8]);
        }
        return;
    }
    // ---- bias concat [bq | bk | bv]
    for (int i = tid; i < E_DIM + 2 * HD; i += 256)
        bqkv[i] = (i < E_DIM) ? bq[i] : (i < E_DIM + HD ? bk[i - E_DIM] : bv[i - E_DIM - HD]);
}

// ---------------- bf16 GEMM v3: 64x128 tile, BK=64, gload_lds staging (r11 best) ----------------
// VTB: for the qkv GEMM, columns >= nQ+HD (the V head) are ALSO scattered to
// vtb[d][s] (Vᵀ), eliminating the separate transpose dispatch.
template<typename OutT, bool VTB>
__global__ __launch_bounds__(256)
void gemm_bt3_kernel(const __hip_bfloat16* __restrict__ A,
                     const __hip_bfloat16* __restrict__ Bt,
                     const float* __restrict__ bias,
                     OutT* __restrict__ C,
                     __hip_bfloat16* __restrict__ vtb,
                     int M, int N, int K, float sQ, int nQ, float sKV) {
    constexpr int BM = 64, BN = 128, BK = 64;
    __shared__ __align__(16) unsigned char lA[2][BM * BK * 2];   // 8KB each
    __shared__ __align__(16) unsigned char lB[2][BN * BK * 2];   // 16KB each
    const int ntn = N / BN;
    const int tm = blockIdx.x / ntn, tn = blockIdx.x % ntn;
    const int tid = threadIdx.x, lane = tid & 63, wave = tid >> 6;
    const int l15 = lane & 15, l4 = lane >> 4;
    const int wm = (wave >> 1) * 32, wn = (wave & 1) * 64;
    const int r0 = tm * BM, c0 = tn * BN;
    const int NK = K / BK;

    size_t aoff[2]; unsigned ldsoA[2];
    size_t boff[4]; unsigned ldsoB[4];
#pragma unroll
    for (int i = 0; i < 2; ++i) {
        int row = wave * 16 + i * 8 + (lane >> 3);
        int c = (lane & 7) ^ (row & 7);
        aoff[i] = (size_t)(r0 + row) * K * 2 + c * 16;
        ldsoA[i] = wave * 2048 + i * 1024;
    }
#pragma unroll
    for (int i = 0; i < 4; ++i) {
        int row = wave * 32 + i * 8 + (lane >> 3);
        int c = (lane & 7) ^ (row & 7);
        boff[i] = (size_t)(c0 + row) * K * 2 + c * 16;
        ldsoB[i] = wave * 4096 + i * 1024;
    }
    const char* Ab = (const char*)A;
    const char* Bb = (const char*)Bt;

#pragma unroll
    for (int i = 0; i < 2; ++i) gload_lds16(Ab + aoff[i], &lA[0][ldsoA[i]]);
#pragma unroll
    for (int i = 0; i < 4; ++i) gload_lds16(Bb + boff[i], &lB[0][ldsoB[i]]);
    __syncthreads();

    f32x4 z4 = {0.f, 0.f, 0.f, 0.f};
    f32x4 acc[2][4];
#pragma unroll
    for (int mi = 0; mi < 2; ++mi)
#pragma unroll
        for (int ni = 0; ni < 4; ++ni) acc[mi][ni] = z4;

    int buf = 0;
    for (int ks = 0; ks < NK; ++ks) {
        if (ks + 1 < NK) {
            size_t kb = (size_t)(ks + 1) * BK * 2;
#pragma unroll
            for (int i = 0; i < 2; ++i) gload_lds16(Ab + aoff[i] + kb, &lA[buf ^ 1][ldsoA[i]]);
#pragma unroll
            for (int i = 0; i < 4; ++i) gload_lds16(Bb + boff[i] + kb, &lB[buf ^ 1][ldsoB[i]]);
        }
        bf16x8 af[2][2], bf[4][2];
#pragma unroll
        for (int mi = 0; mi < 2; ++mi) {
            int row = wm + mi * 16 + l15;
#pragma unroll
            for (int kh = 0; kh < 2; ++kh) {
                int slot = (kh * 4 + l4) ^ (row & 7);
                af[mi][kh] = *reinterpret_cast<const bf16x8*>(&lA[buf][row * 128 + slot * 16]);
            }
        }
#pragma unroll
        for (int ni = 0; ni < 4; ++ni) {
            int row = wn + ni * 16 + l15;
#pragma unroll
            for (int kh = 0; kh < 2; ++kh) {
                int slot = (kh * 4 + l4) ^ (row & 7);
                bf[ni][kh] = *reinterpret_cast<const bf16x8*>(&lB[buf][row * 128 + slot * 16]);
            }
        }
        __builtin_amdgcn_s_setprio(1);
#pragma unroll
        for (int mi = 0; mi < 2; ++mi)
#pragma unroll
            for (int ni = 0; ni < 4; ++ni) {
                acc[mi][ni] = __builtin_amdgcn_mfma_f32_16x16x32_bf16(af[mi][0], bf[ni][0], acc[mi][ni], 0, 0, 0);
                acc[mi][ni] = __builtin_amdgcn_mfma_f32_16x16x32_bf16(af[mi][1], bf[ni][1], acc[mi][ni], 0, 0, 0);
            }
        __builtin_amdgcn_s_setprio(0);
        __syncthreads();
        buf ^= 1;
    }

#pragma unroll
    for (int ni = 0; ni < 4; ++ni) {
        int col = c0 + wn + ni * 16 + l15;
        float b = bias[col];
        float s = (col < nQ) ? sQ : sKV;
#pragma unroll
        for (int mi = 0; mi < 2; ++mi) {
            int row = r0 + wm + mi * 16 + l4 * 4;
#pragma unroll
            for (int r = 0; r < 4; ++r) {
                float v = (acc[mi][ni][r] + b) * s;
                storeOut(C + (size_t)(row + r) * N + col, v);
                if constexpr (VTB) {
                    if (col >= nQ + HD)   // V columns -> vtb[d][s]
                        vtb[(size_t)(col - nQ - HD) * M + row + r] = __float2bfloat16(v);
                }
            }
        }
    }
}

// ---------------- MQA flash attention v10: static-max softmax + 2-waves/SIMD budget ----------------
// grid (S/32, NH/4). 4 waves/block, wave = head, 32 q-rows. Swapped QK^T (q lane-local),
// Oᵀ PV, setprio, gload_lds with pre-swizzled source, lacc ones-MFMA rowsum.
// Softmax is scale-invariant: p = exp2(s) directly (log2-domain logits; masked = -14427 -> p = 0).
// __launch_bounds__(256, 2): min 2 waves/EU forces total (VGPR+AGPR) <= 256/wave so
// 2 blocks/CU stay resident (r9 lesson: without it 168+AGPR > 256 -> 1 wave/SIMD).
// LDS tile: 128 rows x 256B. Row r: chunks 0..7 = K[k0+r][0:64];
// chunks 8..15 = Vt[d = r&63][k-half r>>6]. Chunk c at slot c ^ (r&15).
__global__ __launch_bounds__(256, 2)
void mqa10_kernel(const __hip_bfloat16* __restrict__ qkv,   // [S][1152], q prescaled
                  const __hip_bfloat16* __restrict__ vtb,   // [64][S]
                  const unsigned long long* __restrict__ mbits,
                  __hip_bfloat16* __restrict__ attnb,
                  int S) {
    __shared__ __align__(16) unsigned char sKV[2][32768];
    const int tid = threadIdx.x, lane = tid & 63, w = tid >> 6;
    const int r31 = lane & 31, hi = lane >> 5, rx = r31 & 15;
    const int q0 = blockIdx.x * 32;
    const int h = blockIdx.y * 4 + w;
    const int NT = S / 128, NW64 = S / 64;
    const __hip_bfloat16* kvb = qkv + E_DIM;

    // Q fragments (prescaled by 0.125*log2e in the fused GEMM)
    bf16x8 qf[4];
    {
        const __hip_bfloat16* qp = qkv + (size_t)(q0 + r31) * QKV_LD + h * HD + hi * 8;
#pragma unroll
        for (int s = 0; s < 4; ++s) qf[s] = *reinterpret_cast<const bf16x8*>(qp + 16 * s);
    }
    bf16x8 ones;
#pragma unroll
    for (int i = 0; i < 8; ++i) ones[i] = (__bf16)1.0f;

    // staging: wave w owns tile rows [w*32, w*32+32) -> 8 x 1KB global_load_lds_dwordx4
    const char* gbase[8];
    int gstep[8];
    unsigned ldsoff[8];
#pragma unroll
    for (int i = 0; i < 8; ++i) {
        int r = w * 32 + i * 4 + (lane >> 4);
        int sl = lane & 15;            // LDS 16B slot within row
        int c = sl ^ (r & 15);         // global chunk that lands in this slot
        if (c < 8) {
            gbase[i] = (const char*)(kvb + (size_t)r * QKV_LD + c * 8);
            gstep[i] = 128 * QKV_LD * 2;
        } else {
            gbase[i] = (const char*)(vtb + (size_t)(r & 63) * S + (r >> 6) * 64 + (c - 8) * 8);
            gstep[i] = 128 * 2;
        }
        ldsoff[i] = w * 8192 + i * 1024;
    }

    // prologue: stage tile 0
#pragma unroll
    for (int i = 0; i < 8; ++i) { gload_lds16(gbase[i], &sKV[0][ldsoff[i]]); gbase[i] += gstep[i]; }
    __syncthreads();

    f32x16 oacc[2], lacc;
#pragma unroll
    for (int i = 0; i < 16; ++i) { oacc[0][i] = 0.f; oacc[1][i] = 0.f; lacc[i] = 0.f; }

    const size_t mrow = (size_t)(q0 + r31) * NW64;
    int buf = 0;
    for (int t = 0; t < NT; ++t) {
        // mask words FIRST (so waiting on them never drains the staging queue)
        ulonglong2 wb = *reinterpret_cast<const ulonglong2*>(mbits + mrow + 2 * t);
        // stage tile t+1 into other buffer (drained by end-of-iter barrier)
        if (t + 1 < NT) {
#pragma unroll
            for (int i = 0; i < 8; ++i) { gload_lds16(gbase[i], &sKV[buf ^ 1][ldsoff[i]]); gbase[i] += gstep[i]; }
        }
        const unsigned char* bp = sKV[buf];

        // ---- QK^T: sacc[kb][reg] = S_log2[k = kb*32 + crow(reg,hi)][q = r31]
        f32x16 sacc[4];
        __builtin_amdgcn_s_setprio(1);
#pragma unroll
        for (int kb = 0; kb < 4; ++kb) {
            const unsigned char* rowp = bp + (kb * 32 + r31) * 256;
            f32x16 a;
#pragma unroll
            for (int i = 0; i < 16; ++i) a[i] = 0.f;
#pragma unroll
            for (int s = 0; s < 4; ++s) {
                int slot = (2 * s + hi) ^ rx;
                bf16x8 kf = *reinterpret_cast<const bf16x8*>(rowp + slot * 16);
                a = __builtin_amdgcn_mfma_f32_32x32x16_bf16(kf, qf[s], a, 0, 0, 0);
            }
            sacc[kb] = a;
        }
        __builtin_amdgcn_s_setprio(0);

        // ---- mask (free when all-ones); -10000 * log2e -> exp2 gives exact 0
        if ((wb.x & wb.y) != ~0ull) {
#pragma unroll
            for (int kb = 0; kb < 4; ++kb) {
                unsigned long long wv = (kb < 2) ? wb.x : wb.y;
                int base = (kb & 1) * 32;
#pragma unroll
                for (int r = 0; r < 16; ++r) {
                    int kl = base + (r & 3) + 8 * (r >> 2) + 4 * hi;
                    if (!((wv >> kl) & 1)) sacc[kb][r] = -14427.0f;
                }
            }
        }

        // ---- p = exp2(s) directly: softmax is scale-invariant, no max needed
#pragma unroll
        for (int kb = 0; kb < 4; ++kb)
#pragma unroll
            for (int r = 0; r < 16; ++r) sacc[kb][r] = fexp2(sacc[kb][r]);

        // ---- two phases: build pa[4] (16 VGPRs) then PV + lacc MFMAs
#pragma unroll
        for (int j = 0; j < 2; ++j) {
            bf16x8 pa[4];
#pragma unroll
            for (int kk = 0; kk < 2; ++kk) {          // kb = 2j + kk
#pragma unroll
                for (int half = 0; half < 2; ++half) {
                    int b0 = half * 8;
                    const f32x16& sv = sacc[2 * j + kk];
                    unsigned A = cvtpk_bf16(sv[b0 + 0], sv[b0 + 1]);
                    unsigned B = cvtpk_bf16(sv[b0 + 2], sv[b0 + 3]);
                    unsigned C = cvtpk_bf16(sv[b0 + 4], sv[b0 + 5]);
                    unsigned D = cvtpk_bf16(sv[b0 + 6], sv[b0 + 7]);
                    perm32swap(A, C);
                    perm32swap(B, D);
                    union { unsigned u[4]; bf16x8 v; } pk;
                    pk.u[0] = A; pk.u[1] = B; pk.u[2] = C; pk.u[3] = D;
                    pa[kk * 2 + half] = pk.v;
                }
            }
            __builtin_amdgcn_s_setprio(1);
#pragma unroll
            for (int db = 0; db < 2; ++db) {
                const unsigned char* rowp = bp + (j * 64 + db * 32 + r31) * 256;
                f32x16 a = oacc[db];
#pragma unroll
                for (int s = 0; s < 4; ++s) {
                    int slot = (8 + 2 * s + hi) ^ rx;
                    bf16x8 vf = *reinterpret_cast<const bf16x8*>(rowp + slot * 16);
                    a = __builtin_amdgcn_mfma_f32_32x32x16_bf16(vf, pa[s], a, 0, 0, 0);
                }
                oacc[db] = a;
            }
#pragma unroll
            for (int s = 0; s < 4; ++s)
                lacc = __builtin_amdgcn_mfma_f32_32x32x16_bf16(ones, pa[s], lacc, 0, 0, 0);
            __builtin_amdgcn_s_setprio(0);
        }

        __syncthreads();
        buf ^= 1;
    }

    // ---- epilogue: O /= l (lacc rows all equal the row-sum for q = r31)
    float inv = 1.0f / lacc[0];
    __hip_bfloat16* op = attnb + (size_t)(q0 + r31) * E_DIM + h * HD;
#pragma unroll
    for (int db = 0; db < 2; ++db)
#pragma unroll
        for (int m = 0; m < 4; ++m) {
            uint2 pk;
            pk.x = cvtpk_bf16(oacc[db][4 * m + 0] * inv, oacc[db][4 * m + 1] * inv);
            pk.y = cvtpk_bf16(oacc[db][4 * m + 2] * inv, oacc[db][4 * m + 3] * inv);
            *reinterpret_cast<uint2*>(op + db * 32 + m * 8 + hi * 4) = pk;
        }
}

// ---------------- host launch ----------------
extern "C" void kernel_launch(void* const* d_in, const int* in_sizes, int n_in,
                              void* d_out, int out_size, void* d_ws, size_t ws_size,
                              hipStream_t stream) {
    (void)n_in; (void)out_size; (void)ws_size;
    const float* x  = (const float*)d_in[0];
    const int* mask = (const int*)d_in[1];
    const float* Wq = (const float*)d_in[2];
    const float* bq = (const float*)d_in[3];
    const float* Wk = (const float*)d_in[4];
    const float* bk = (const float*)d_in[5];
    const float* Wv = (const float*)d_in[6];
    const float* bv = (const float*)d_in[7];
    const float* Wo = (const float*)d_in[8];
    const float* bo = (const float*)d_in[9];
    float* out = (float*)d_out;

    const int E = E_DIM;
    const int S = in_sizes[0] / E;

    char* ws = (char*)d_ws;
    size_t off = 0;
    auto alloc = [&](size_t b) { char* p = ws + off; off += (b + 255) & ~(size_t)255; return p; };
    __hip_bfloat16* xb     = (__hip_bfloat16*)alloc((size_t)S * E * 2);
    __hip_bfloat16* wqkvT  = (__hip_bfloat16*)alloc((size_t)QKV_LD * E * 2);  // [Wq^T;Wk^T;Wv^T]
    __hip_bfloat16* woT    = (__hip_bfloat16*)alloc((size_t)E * E * 2);
    __hip_bfloat16* qkvb   = (__hip_bfloat16*)alloc((size_t)S * QKV_LD * 2);
    __hip_bfloat16* vtb    = (__hip_bfloat16*)alloc((size_t)HD * S * 2);
    __hip_bfloat16* attnb  = (__hip_bfloat16*)alloc((size_t)S * E * 2);
    float* bqkv  = (float*)alloc(QKV_LD * 4);
    unsigned long long* mbits = (unsigned long long*)alloc((size_t)S * (S / 64) * 8);

    // fused prep: cast | maskbits | weight transposes | bias concat (one dispatch)
    const int prepBlocks = (S * E / 1024) + 1024 + 2176 + 1;
    prep_kernel<<<dim3(prepBlocks), dim3(256), 0, stream>>>(
        x, xb, mask, mbits, Wq, Wk, Wv, Wo, wqkvT, woT, bq, bk, bv, bqkv, S);

    // fused qkv = x @ [Wq|Wk|Wv] + [bq|bk|bv]; q-part scaled by 1/8*log2e -> bf16 [S][1152]
    // V columns also scattered to vtb (V^T) in the epilogue.
    gemm_bt3_kernel<__hip_bfloat16, true><<<dim3((S / 64) * (QKV_LD / 128)), dim3(256), 0, stream>>>(
        xb, wqkvT, bqkv, qkvb, vtb, S, QKV_LD, E, 0.125f * LOG2E, E, 1.0f);
    // attention (merged-head MQA, swapped-QK^T flash, KVBLK=128, static-max softmax)
    mqa10_kernel<<<dim3(S / 32, NH / 4), dim3(256), 0, stream>>>(qkvb, vtb, mbits, attnb, S);
    // out = attn @ Wo + bo  (fp32)
    gemm_bt3_kernel<float, false><<<dim3((S / 64) * (E / 128)), dim3(256), 0, stream>>>(
        attnb, woT, bo, out, nullptr, S, E, E, 1.0f, E, 1.0f);
}